// Round 1
// baseline (32834.851 us; speedup 1.0000x reference)
//
#include <hip/hip_runtime.h>

typedef unsigned int u32;
typedef unsigned short u16;
typedef unsigned long long u64;

#define T_STEPS 2048
#define BATCH   32
#define HID     512
#define INDIM   128
#define OUTD    128
#define NG      2048
#define L0_WGS  64
#define L1_WGS  64
#define FC_WGS  4
#define NWG     (L0_WGS + L1_WGS + FC_WGS)

#define HID_OFF 8388608           // 32*2048*128
#define CN_OFF  8396800           // + 2*32*128

// Tagged ring: 16 slots, each slot = 32 rows x 256 chunks of 8B.
// chunk u64 = (tag<<32) | (bf16 col2j+1 <<16) | (bf16 col2j); tag = t+1.
#define RSLOT_U16 32768           // u16 per slot (64 KB)
#define RING_B    1048576         // 16 slots

// ws layout (bytes)
#define WS_FLAGS   0                          // 132 flags, 64B stride (16 KB reserved)
#define WS_H0RING  16384
#define WS_H1RING  (WS_H0RING + RING_B)
#define WS_BIAS0   (WS_H1RING + RING_B)
#define WS_BIAS1   (WS_BIAS0 + 8192)
#define WS_WFC     (WS_BIAS1 + 8192)          // 4 * 16384 u16
#define WS_WL0     (WS_WFC + 131072)          // 64 * 20480 u16
#define WS_WL1     (WS_WL0 + 2621440)         // 64 * 32768 u16
#define WS_XBF     (WS_WL1 + 4194304)         // 32*2048*128 u16

typedef __bf16 bf16x8 __attribute__((ext_vector_type(8)));
typedef float  f32x4  __attribute__((ext_vector_type(4)));
typedef unsigned int u32x4 __attribute__((ext_vector_type(4)));

__device__ __forceinline__ u16 f2bf(float f) {
    u32 u = __float_as_uint(f);
    u32 r = u + 0x7FFFu + ((u >> 16) & 1u);
    return (u16)(r >> 16);
}

union UB2 { u32x4 u; bf16x8 b; };
__device__ __forceinline__ bf16x8 as_bf(u32x4 u) { UB2 x; x.u = u; return x.b; }

__device__ __forceinline__ u32 relu2(u32 u) {
    u32 lo = (u & 0x8000u)     ? 0u : (u & 0xFFFFu);
    u32 hi = (u & 0x80000000u) ? 0u : (u & 0xFFFF0000u);
    return lo | hi;
}

// LLC-coherent 16B load via two compiler-tracked agent-scope 8B atomic loads.
union U64X2 { u64 q[2]; u32x4 v; };
__device__ __forceinline__ u32x4 load_llc(const u16* p) {
    u64* q = (u64*)p;
    U64X2 r;
    r.q[0] = __hip_atomic_load(q + 0, __ATOMIC_RELAXED, __HIP_MEMORY_SCOPE_AGENT);
    r.q[1] = __hip_atomic_load(q + 1, __ATOMIC_RELAXED, __HIP_MEMORY_SCOPE_AGENT);
    return r.v;
}

// Poll 16 k-slices (32B each = 4 tagged chunks) of one h matrix row-fragment.
// First pass is branch-free so all 32 loads pipeline; retry rounds reload all
// (data is immutable once tagged, so overwriting PK with a fresh valid load is safe).
#define POLL16(PK, BASE, TAG)                                               \
  {                                                                         \
    u32 _pend;                                                              \
    do {                                                                    \
      _pend = 0;                                                            \
      _Pragma("unroll")                                                     \
      for (int _ks = 0; _ks < 16; ++_ks) {                                  \
        const u16* _p = (BASE) + _ks * 64 + quad * 16;                      \
        u32x4 _c0 = load_llc(_p);                                           \
        u32x4 _c1 = load_llc(_p + 8);                                       \
        PK[_ks] = (u32x4){_c0[0], _c0[2], _c1[0], _c1[2]};                  \
        _pend |= (_c0[1] ^ (TAG)) | (_c0[3] ^ (TAG)) |                      \
                 (_c1[1] ^ (TAG)) | (_c1[3] ^ (TAG));                       \
      }                                                                     \
    } while (_pend);                                                        \
  }

// 16 MFMAs over a polled matrix, split into two acc chains to halve dep latency.
#define HMFMA16(PK, KSOFF)                                                  \
    _Pragma("unroll")                                                       \
    for (int _k = 0; _k < 16; ++_k) {                                       \
      bf16x8 _bv = wp[wbase + (_k + (KSOFF)) * 128];                        \
      if (_k & 1) accB = __builtin_amdgcn_mfma_f32_16x16x32_bf16(as_bf(PK[_k]), _bv, accB, 0, 0, 0); \
      else        accA = __builtin_amdgcn_mfma_f32_16x16x32_bf16(as_bf(PK[_k]), _bv, accA, 0, 0, 0); \
    }

// ---------------- prep kernels ----------------

__global__ void k_zero(u32* dst, int n) {
    int i = blockIdx.x * blockDim.x + threadIdx.x;
    if (i < n) dst[i] = 0u;
}

__global__ void k_bias(const float* __restrict__ bih0, const float* __restrict__ bhh0,
                       const float* __restrict__ bih1, const float* __restrict__ bhh1,
                       float* __restrict__ bias0, float* __restrict__ bias1) {
    int i = blockIdx.x * blockDim.x + threadIdx.x;
    if (i < NG) {
        int orig = (i & 3) * HID + (i >> 2);
        bias0[i] = bih0[orig] + bhh0[orig];
        bias1[i] = bih1[orig] + bhh1[orig];
    }
}

__global__ void k_xconv(const float* __restrict__ x, u16* __restrict__ xbf) {
    int i = blockIdx.x * blockDim.x + threadIdx.x;   // exactly 2097152 threads
    float4 v = reinterpret_cast<const float4*>(x)[i];
    u32 lo = (u32)f2bf(v.x) | ((u32)f2bf(v.y) << 16);
    u32 hi = (u32)f2bf(v.z) | ((u32)f2bf(v.w) << 16);
    reinterpret_cast<uint2*>(xbf)[i] = make_uint2(lo, hi);
}

// LDS-ready layout per WG: [ks][kb(4)][n(32)][8], value = W[p = wg*32+n][k = 32ks+8kb+j]
__global__ void k_wconv(const float* __restrict__ wih0, const float* __restrict__ whh0,
                        const float* __restrict__ wih1, const float* __restrict__ whh1,
                        const float* __restrict__ fcw,
                        u16* __restrict__ wl0, u16* __restrict__ wl1, u16* __restrict__ wfc) {
    int i = blockIdx.x * blockDim.x + threadIdx.x;   // exactly 3473408 threads
    if (i < 64 * 20480) {                            // layer0: K=640 (512 hh + 128 ih)
        int wg = i / 20480, r = i % 20480;
        int ks = r / 1024, kb = (r % 1024) / 256, n = (r % 256) / 8, j = r % 8;
        int k = ks * 32 + kb * 8 + j;
        int p = wg * 32 + n;
        int orig = (p & 3) * HID + (p >> 2);
        float v = (k < HID) ? whh0[orig * HID + k] : wih0[orig * INDIM + (k - HID)];
        wl0[i] = f2bf(v);
        return;
    }
    int i1 = i - 64 * 20480;
    if (i1 < 64 * 32768) {                           // layer1: K=1024 (512 ih(h0) + 512 hh(h1))
        int wg = i1 / 32768, r = i1 % 32768;
        int ks = r / 1024, kb = (r % 1024) / 256, n = (r % 256) / 8, j = r % 8;
        int k = ks * 32 + kb * 8 + j;
        int p = wg * 32 + n;
        int orig = (p & 3) * HID + (p >> 2);
        float v = (k < HID) ? wih1[orig * HID + k] : whh1[orig * HID + (k - HID)];
        wl1[i1] = f2bf(v);
        return;
    }
    int i2 = i1 - 64 * 32768;
    if (i2 < 4 * 16384) {                            // fc: K=512, no row permutation
        int wg = i2 / 16384, r = i2 % 16384;
        int ks = r / 1024, kb = (r % 1024) / 256, n = (r % 256) / 8, j = r % 8;
        int k = ks * 32 + kb * 8 + j;
        int o = wg * 32 + n;
        wfc[i2] = f2bf(fcw[o * HID + k]);
    }
}

// ---------------- persistent fused LSTM ----------------
//
// Sync protocol (v2, tagged dataflow):
//  * forward dep (h[t] ready): consumers poll the tagged 8B chunks directly.
//    No producer vmcnt(0) drain, no forward flags.  tag = t+1 (init 0 never matches).
//  * backward dep (ring WAR, 16-deep): flags[wg] = "finished loads of step t"
//    published each step (fire-and-forget); producers check with 14-step slack,
//    only every 8th step (target t-6 covers overwrites t..t+7).

__global__ __launch_bounds__(256, 1)
void k_lstm(const u16* __restrict__ xbf,
            const u16* __restrict__ wl0g, const u16* __restrict__ wl1g, const u16* __restrict__ wfcg,
            const float* __restrict__ bias0, const float* __restrict__ bias1, const float* __restrict__ fcb,
            u16* __restrict__ h0ring, u16* __restrict__ h1ring,
            u32* __restrict__ flags, float* __restrict__ dout)
{
    __shared__ u16 wlds[32768];                      // 64 KB
    const int tid  = threadIdx.x;
    const int lane = tid & 63;
    const int wv   = tid >> 6;
    const int mt   = wv >> 1;                        // batch-half tile
    const int nt   = wv & 1;                         // col tile
    const int ci   = lane & 15;
    const int quad = lane >> 4;
    const int wg   = blockIdx.x;

    int role, rwg;
    if      (wg < L0_WGS)           { role = 0; rwg = wg; }
    else if (wg < L0_WGS + L1_WGS)  { role = 1; rwg = wg - L0_WGS; }
    else                            { role = 2; rwg = wg - L0_WGS - L1_WGS; }

    u32* myflag = flags + wg * 16;                   // 64B stride

    {   // stage this WG's weight slice into LDS (once)
        const u16* src = (role == 0) ? (wl0g + rwg * 20480)
                       : (role == 1) ? (wl1g + rwg * 32768)
                                     : (wfcg + rwg * 16384);
        const int n4 = (role == 0) ? 2560 : (role == 1) ? 4096 : 2048;
        uint4* d4 = reinterpret_cast<uint4*>(wlds);
        const uint4* s4 = reinterpret_cast<const uint4*>(src);
        for (int i = tid; i < n4; i += 256) d4[i] = s4[i];
    }
    __syncthreads();

    const bf16x8* wp = reinterpret_cast<const bf16x8*>(wlds);
    const int wbase  = quad * 32 + nt * 16 + ci;     // + ks*128
    const int pcol   = rwg * 32 + nt * 16 + ci;      // permuted gate col (roles 0/1) or out col (fc)
    const int gateid = pcol & 3;                     // 0=i 1=f 2=g 3=o
    const float bias = (role == 0) ? bias0[pcol] : (role == 1) ? bias1[pcol] : fcb[pcol];
    const int brow0  = mt * 16 + quad * 4;           // C/D: batch of acc reg r is brow0+r
    const int arow   = mt * 16 + ci;                 // A-frag batch row
    const int jidx   = pcol >> 2;                    // h index owned (roles 0/1)

    float cst[4] = {0.f, 0.f, 0.f, 0.f};             // c-state, f32, replicated x4 lanes

    auto spin = [&](u32* f, int target) {
        if (target > 0)
            while ((int)__hip_atomic_load(f, __ATOMIC_RELAXED, __HIP_MEMORY_SCOPE_AGENT) < target)
                __builtin_amdgcn_s_sleep(1);
    };

    // epilogue: gates -> c,h; shfl-transpose so lanes ci<4 store one row's
    // 4 contiguous cols as two tagged 8B atomic chunks (aligned, fire-and-forget).
    auto epi = [&](const f32x4& acc, u16* slotb, u32 tag) {
        float ga[4], hv[4];
        #pragma unroll
        for (int r = 0; r < 4; ++r) {
            float g  = acc[r] + bias;
            float sv = 1.0f / (1.0f + __expf(-g));
            float tv = 1.0f - 2.0f / (__expf(2.0f * g) + 1.0f);
            ga[r] = (gateid == 2) ? tv : sv;
        }
        const int bl = lane & ~3;
        #pragma unroll
        for (int r = 0; r < 4; ++r) {
            float iv = __shfl(ga[r], bl + 0);
            float fv = __shfl(ga[r], bl + 1);
            float gv = __shfl(ga[r], bl + 2);
            float ov = __shfl(ga[r], bl + 3);
            float cn = fv * cst[r] + iv * gv;
            cst[r] = cn;
            hv[r] = ov * (1.0f - 2.0f / (__expf(2.0f * cn) + 1.0f));
        }
        u32 lo = 0, hi = 0;
        #pragma unroll
        for (int r = 0; r < 4; ++r) {                // gather row brow0+r into lane ci==r
            float c0 = __shfl(hv[r], (quad << 4) + 0);
            float c1 = __shfl(hv[r], (quad << 4) + 4);
            float c2 = __shfl(hv[r], (quad << 4) + 8);
            float c3 = __shfl(hv[r], (quad << 4) + 12);
            if (ci == r) {
                lo = (u32)f2bf(c0) | ((u32)f2bf(c1) << 16);
                hi = (u32)f2bf(c2) | ((u32)f2bf(c3) << 16);
            }
        }
        if (ci < 4) {
            u64* dst = reinterpret_cast<u64*>(slotb) + (brow0 + ci) * 256 + rwg * 4 + nt * 2;
            u64 tg = (u64)tag << 32;
            __hip_atomic_store(dst,     tg | lo, __ATOMIC_RELAXED, __HIP_MEMORY_SCOPE_AGENT);
            __hip_atomic_store(dst + 1, tg | hi, __ATOMIC_RELAXED, __HIP_MEMORY_SCOPE_AGENT);
        }
    };

    if (role == 0) {
        for (int t = 0; t < T_STEPS; ++t) {
            // x-part MFMAs don't depend on h: run before the h-poll
            const u16* xA = xbf + (arow * T_STEPS + t) * INDIM + quad * 8;
            f32x4 accA = {0.f, 0.f, 0.f, 0.f}, accB = {0.f, 0.f, 0.f, 0.f};
            u32x4 xv[4];
            #pragma unroll
            for (int k4 = 0; k4 < 4; ++k4) xv[k4] = *reinterpret_cast<const u32x4*>(xA + k4 * 32);
            #pragma unroll
            for (int k4 = 0; k4 < 4; ++k4) {
                bf16x8 bv = wp[wbase + (16 + k4) * 128];
                if (k4 & 1) accB = __builtin_amdgcn_mfma_f32_16x16x32_bf16(as_bf(xv[k4]), bv, accB, 0, 0, 0);
                else        accA = __builtin_amdgcn_mfma_f32_16x16x32_bf16(as_bf(xv[k4]), bv, accA, 0, 0, 0);
            }
            if (t > 0) {                              // h0[t-1]: tag t, slot (t-1)&15
                const u16* hb = h0ring + ((t + 15) & 15) * RSLOT_U16 + arow * 1024;
                u32x4 pk[16];
                POLL16(pk, hb, (u32)t);
                HMFMA16(pk, 0);
            }
            // WAR gate (h0 readers = L0+L1 = flags 0..127), every 8 steps, 14-step slack
            if ((t & 7) == 0 && tid < 128) spin(flags + tid * 16, t - 6);
            __syncthreads();                          // all waves: loads done + WAR passed
            if (tid == 0)
                __hip_atomic_store(myflag, (u32)(t + 1), __ATOMIC_RELAXED, __HIP_MEMORY_SCOPE_AGENT);
            epi(accA + accB, h0ring + (t & 15) * RSLOT_U16, (u32)(t + 1));
        }
    } else if (role == 1) {
        for (int t = 0; t < T_STEPS; ++t) {
            f32x4 accA = {0.f, 0.f, 0.f, 0.f}, accB = {0.f, 0.f, 0.f, 0.f};
            {                                         // h0[t]: tag t+1, slot t&15  (W_ih1)
                const u16* hb = h0ring + (t & 15) * RSLOT_U16 + arow * 1024;
                u32x4 pk[16];
                POLL16(pk, hb, (u32)(t + 1));
                HMFMA16(pk, 0);
            }
            if (t > 0) {                              // h1[t-1]: tag t, slot (t-1)&15  (W_hh1)
                const u16* hb = h1ring + ((t + 15) & 15) * RSLOT_U16 + arow * 1024;
                u32x4 pk[16];
                POLL16(pk, hb, (u32)t);
                HMFMA16(pk, 16);
            }
            // WAR gate (h1 readers = L1+FC = flags 64..131), every 8 steps
            if ((t & 7) == 0 && tid < 68) spin(flags + (64 + tid) * 16, t - 6);
            __syncthreads();
            if (tid == 0)
                __hip_atomic_store(myflag, (u32)(t + 1), __ATOMIC_RELAXED, __HIP_MEMORY_SCOPE_AGENT);
            epi(accA + accB, h1ring + (t & 15) * RSLOT_U16, (u32)(t + 1));
        }
    } else {
        for (int t = 0; t < T_STEPS; ++t) {
            const u16* hb = h1ring + (t & 15) * RSLOT_U16 + arow * 1024;
            u32x4 pk[16];
            POLL16(pk, hb, (u32)(t + 1));
            f32x4 accA = {0.f, 0.f, 0.f, 0.f}, accB = {0.f, 0.f, 0.f, 0.f};
            #pragma unroll
            for (int ks = 0; ks < 16; ++ks) {
                u32x4 v = pk[ks];
                v[0] = relu2(v[0]); v[1] = relu2(v[1]); v[2] = relu2(v[2]); v[3] = relu2(v[3]);
                bf16x8 bv = wp[wbase + ks * 128];
                if (ks & 1) accB = __builtin_amdgcn_mfma_f32_16x16x32_bf16(as_bf(v), bv, accB, 0, 0, 0);
                else        accA = __builtin_amdgcn_mfma_f32_16x16x32_bf16(as_bf(v), bv, accA, 0, 0, 0);
            }
            f32x4 acc = accA + accB;
            #pragma unroll
            for (int r = 0; r < 4; ++r)
                dout[((brow0 + r) * T_STEPS + t) * OUTD + pcol] = acc[r] + bias;
            __syncthreads();                          // all waves' loads of slot done
            if (tid == 0)
                __hip_atomic_store(myflag, (u32)(t + 1), __ATOMIC_RELAXED, __HIP_MEMORY_SCOPE_AGENT);
        }
        // hidden = fc(relu(h_n)); h[2047] lives in slot 15 (tag 2048), never overwritten
        #pragma unroll
        for (int l = 0; l < 2; ++l) {
            const u16* hb = (l == 0 ? h0ring : h1ring) + 15 * RSLOT_U16 + arow * 1024;
            u32x4 pk[16];
            POLL16(pk, hb, 2048u);
            f32x4 accA = {0.f, 0.f, 0.f, 0.f}, accB = {0.f, 0.f, 0.f, 0.f};
            #pragma unroll
            for (int ks = 0; ks < 16; ++ks) {
                u32x4 v = pk[ks];
                v[0] = relu2(v[0]); v[1] = relu2(v[1]); v[2] = relu2(v[2]); v[3] = relu2(v[3]);
                bf16x8 bv = wp[wbase + ks * 128];
                if (ks & 1) accB = __builtin_amdgcn_mfma_f32_16x16x32_bf16(as_bf(v), bv, accB, 0, 0, 0);
                else        accA = __builtin_amdgcn_mfma_f32_16x16x32_bf16(as_bf(v), bv, accA, 0, 0, 0);
            }
            f32x4 hh = accA + accB;
            #pragma unroll
            for (int r = 0; r < 4; ++r)
                dout[HID_OFF + (l * BATCH + brow0 + r) * OUTD + pcol] = hh[r] + bias;
        }
    }

    // c_n output [2, 32, 512]
    if (role <= 1 && (ci & 3) == 0) {
        #pragma unroll
        for (int r = 0; r < 4; ++r)
            dout[CN_OFF + (role * BATCH + brow0 + r) * HID + jidx] = cst[r];
    }
}

// ---------------- launch ----------------

extern "C" void kernel_launch(void* const* d_in, const int* in_sizes, int n_in,
                              void* d_out, int out_size, void* d_ws, size_t ws_size,
                              hipStream_t stream) {
    const float* x    = (const float*)d_in[0];
    const float* wih0 = (const float*)d_in[1];
    const float* whh0 = (const float*)d_in[2];
    const float* bih0 = (const float*)d_in[3];
    const float* bhh0 = (const float*)d_in[4];
    const float* wih1 = (const float*)d_in[5];
    const float* whh1 = (const float*)d_in[6];
    const float* bih1 = (const float*)d_in[7];
    const float* bhh1 = (const float*)d_in[8];
    const float* fcw  = (const float*)d_in[9];
    const float* fcb  = (const float*)d_in[10];

    char* ws = (char*)d_ws;
    u32*  flags = (u32*)(ws + WS_FLAGS);
    u16*  h0r   = (u16*)(ws + WS_H0RING);
    u16*  h1r   = (u16*)(ws + WS_H1RING);
    float* b0   = (float*)(ws + WS_BIAS0);
    float* b1   = (float*)(ws + WS_BIAS1);
    u16*  wfc   = (u16*)(ws + WS_WFC);
    u16*  wl0   = (u16*)(ws + WS_WL0);
    u16*  wl1   = (u16*)(ws + WS_WL1);
    u16*  xbf   = (u16*)(ws + WS_XBF);
    float* dout = (float*)d_out;

    // zero flags + both tagged rings (tags 0 never match; ws re-poisoned per call)
    k_zero<<<2064, 256, 0, stream>>>((u32*)ws, 528384);
    k_bias<<<8, 256, 0, stream>>>(bih0, bhh0, bih1, bhh1, b0, b1);
    k_xconv<<<8192, 256, 0, stream>>>(x, xbf);
    k_wconv<<<13568, 256, 0, stream>>>(wih0, whh0, wih1, whh1, fcw, wl0, wl1, wfc);
    k_lstm<<<NWG, 256, 0, stream>>>(xbf, wl0, wl1, wfc, b0, b1, fcb,
                                    h0r, h1r, flags, dout);
}

// Round 2
// 18548.933 us; speedup vs baseline: 1.7702x; 1.7702x over previous
//
#include <hip/hip_runtime.h>

typedef unsigned int u32;
typedef unsigned short u16;
typedef unsigned long long u64;

#define T_STEPS 2048
#define BATCH   32
#define HID     512
#define INDIM   128
#define OUTD    128
#define NG      2048
#define L0_WGS  64
#define L1_WGS  64
#define FC_WGS  4
#define NWG     (L0_WGS + L1_WGS + FC_WGS)
#define HEAT_WGS 124
#define GRID    (NWG + HEAT_WGS)
#define BH      (BATCH * HID)

#define HID_OFF 8388608           // 32*2048*128
#define CN_OFF  8396800           // + 2*32*128

// ws layout (bytes)
#define WS_FLAGS   0                         // 132 flags, 64B stride (16 KB reserved)
#define WS_H0RING  16384
#define WS_H1RING  (WS_H0RING + 131072)      // 4*32*512*2
#define WS_BIAS0   (WS_H1RING + 131072)
#define WS_BIAS1   (WS_BIAS0 + 8192)
#define WS_WFC     (WS_BIAS1 + 8192)         // 4 * 16384 u16
#define WS_WL0     (WS_WFC + 131072)         // 64 * 20480 u16
#define WS_WL1     (WS_WL0 + 2621440)        // 64 * 32768 u16
#define WS_XBF     (WS_WL1 + 4194304)        // 32*2048*128 u16

typedef __bf16 bf16x8 __attribute__((ext_vector_type(8)));
typedef float  f32x4  __attribute__((ext_vector_type(4)));
typedef unsigned int u32x4 __attribute__((ext_vector_type(4)));

__device__ __forceinline__ u16 f2bf(float f) {
    u32 u = __float_as_uint(f);
    u32 r = u + 0x7FFFu + ((u >> 16) & 1u);
    return (u16)(r >> 16);
}

union UB2 { u32x4 u; bf16x8 b; };
__device__ __forceinline__ bf16x8 as_bf(u32x4 u) { UB2 x; x.u = u; return x.b; }

__device__ __forceinline__ u32 relu2(u32 u) {
    u32 lo = (u & 0x8000u)     ? 0u : (u & 0xFFFFu);
    u32 hi = (u & 0x80000000u) ? 0u : (u & 0xFFFF0000u);
    return lo | hi;
}

// LLC-coherent 16B load via two compiler-tracked agent-scope atomic loads.
union U64X2 { u64 q[2]; u32x4 v; };
__device__ __forceinline__ u32x4 load_llc(const u16* p) {
    u64* q = (u64*)p;
    U64X2 r;
    r.q[0] = __hip_atomic_load(q + 0, __ATOMIC_RELAXED, __HIP_MEMORY_SCOPE_AGENT);
    r.q[1] = __hip_atomic_load(q + 1, __ATOMIC_RELAXED, __HIP_MEMORY_SCOPE_AGENT);
    return r.v;
}
__device__ __forceinline__ void vm0() {          // drain own stores to coherence point
    asm volatile("s_waitcnt vmcnt(0)" ::: "memory");
}

// 16 MFMAs over 16 k-slices, two acc chains to halve dep latency.
#define HMFMA16(PK, KSOFF)                                                  \
    _Pragma("unroll")                                                       \
    for (int _k = 0; _k < 16; ++_k) {                                       \
      bf16x8 _bv = wp[wbase + (_k + (KSOFF)) * 128];                        \
      if (_k & 1) accB = __builtin_amdgcn_mfma_f32_16x16x32_bf16(as_bf(PK[_k]), _bv, accB, 0, 0, 0); \
      else        accA = __builtin_amdgcn_mfma_f32_16x16x32_bf16(as_bf(PK[_k]), _bv, accA, 0, 0, 0); \
    }

// ---------------- prep kernels ----------------

__global__ void k_zero(u32* dst, int n) {
    int i = blockIdx.x * blockDim.x + threadIdx.x;
    if (i < n) dst[i] = 0u;
}

__global__ void k_bias(const float* __restrict__ bih0, const float* __restrict__ bhh0,
                       const float* __restrict__ bih1, const float* __restrict__ bhh1,
                       float* __restrict__ bias0, float* __restrict__ bias1) {
    int i = blockIdx.x * blockDim.x + threadIdx.x;
    if (i < NG) {
        int orig = (i & 3) * HID + (i >> 2);
        bias0[i] = bih0[orig] + bhh0[orig];
        bias1[i] = bih1[orig] + bhh1[orig];
    }
}

__global__ void k_xconv(const float* __restrict__ x, u16* __restrict__ xbf) {
    int i = blockIdx.x * blockDim.x + threadIdx.x;   // exactly 2097152 threads
    float4 v = reinterpret_cast<const float4*>(x)[i];
    u32 lo = (u32)f2bf(v.x) | ((u32)f2bf(v.y) << 16);
    u32 hi = (u32)f2bf(v.z) | ((u32)f2bf(v.w) << 16);
    reinterpret_cast<uint2*>(xbf)[i] = make_uint2(lo, hi);
}

// LDS-ready layout per WG: [ks][kb(4)][n(32)][8], value = W[p = wg*32+n][k = 32ks+8kb+j]
__global__ void k_wconv(const float* __restrict__ wih0, const float* __restrict__ whh0,
                        const float* __restrict__ wih1, const float* __restrict__ whh1,
                        const float* __restrict__ fcw,
                        u16* __restrict__ wl0, u16* __restrict__ wl1, u16* __restrict__ wfc) {
    int i = blockIdx.x * blockDim.x + threadIdx.x;   // exactly 3473408 threads
    if (i < 64 * 20480) {                            // layer0: K=640 (512 hh + 128 ih)
        int wg = i / 20480, r = i % 20480;
        int ks = r / 1024, kb = (r % 1024) / 256, n = (r % 256) / 8, j = r % 8;
        int k = ks * 32 + kb * 8 + j;
        int p = wg * 32 + n;
        int orig = (p & 3) * HID + (p >> 2);
        float v = (k < HID) ? whh0[orig * HID + k] : wih0[orig * INDIM + (k - HID)];
        wl0[i] = f2bf(v);
        return;
    }
    int i1 = i - 64 * 20480;
    if (i1 < 64 * 32768) {                           // layer1: K=1024 (512 ih(h0) + 512 hh(h1))
        int wg = i1 / 32768, r = i1 % 32768;
        int ks = r / 1024, kb = (r % 1024) / 256, n = (r % 256) / 8, j = r % 8;
        int k = ks * 32 + kb * 8 + j;
        int p = wg * 32 + n;
        int orig = (p & 3) * HID + (p >> 2);
        float v = (k < HID) ? wih1[orig * HID + k] : whh1[orig * HID + (k - HID)];
        wl1[i1] = f2bf(v);
        return;
    }
    int i2 = i1 - 64 * 32768;
    if (i2 < 4 * 16384) {                            // fc: K=512, no row permutation
        int wg = i2 / 16384, r = i2 % 16384;
        int ks = r / 1024, kb = (r % 1024) / 256, n = (r % 256) / 8, j = r % 8;
        int k = ks * 32 + kb * 8 + j;
        int o = wg * 32 + n;
        wfc[i2] = f2bf(fcw[o * HID + k]);
    }
}

// ---------------- persistent fused LSTM ----------------
//
// v0 flag protocol (known-good) + three changes:
//  1. heater WGs on the 124 idle CUs: register-only FMA spin until FC WG0's
//     flag reaches T_STEPS.  Theory: at 1-3% utilization the SMU parks SCLK
//     near its floor; busy CUs should restore boost clock, shrinking every
//     LLC round-trip in the serial recurrence chain.
//  2. epi stores h via shfl-transpose as ONE aligned 8B atomic per active
//     lane (16 stores/WG vs 256 scattered 2B) -> faster vmcnt(0) drain,
//     no sub-dword write amplification.
//  3. dual MFMA accumulator chains (halve dep-stall in the 16/32-MFMA runs).

__global__ __launch_bounds__(256, 1)
void k_lstm(const u16* __restrict__ xbf,
            const u16* __restrict__ wl0g, const u16* __restrict__ wl1g, const u16* __restrict__ wfcg,
            const float* __restrict__ bias0, const float* __restrict__ bias1, const float* __restrict__ fcb,
            u16* __restrict__ h0ring, u16* __restrict__ h1ring,
            u32* __restrict__ flags, float* __restrict__ dout)
{
    if (blockIdx.x >= NWG) {                         // ---- heater ----
        u32* done = flags + (L0_WGS + L1_WGS) * 16;  // FC WG0 flag -> T_STEPS at end
        float a = (float)(threadIdx.x + blockIdx.x * 7);
        float b = a * 1.0000001f + 3.0f;
        for (;;) {
            #pragma unroll
            for (int i = 0; i < 256; ++i) {
                a = __builtin_fmaf(a, 1.0000002f, 1e-7f);
                b = __builtin_fmaf(b, 0.9999998f, 1e-7f);
            }
            if (__hip_atomic_load(done, __ATOMIC_RELAXED, __HIP_MEMORY_SCOPE_AGENT) >= T_STEPS)
                break;
        }
        asm volatile("" :: "v"(a), "v"(b));          // keep the FMAs live
        return;
    }

    __shared__ u16 wlds[32768];                      // 64 KB
    const int tid  = threadIdx.x;
    const int lane = tid & 63;
    const int wv   = tid >> 6;
    const int mt   = wv >> 1;                        // batch-half tile
    const int nt   = wv & 1;                         // col tile
    const int ci   = lane & 15;
    const int quad = lane >> 4;
    const int wg   = blockIdx.x;

    int role, rwg;
    if      (wg < L0_WGS)           { role = 0; rwg = wg; }
    else if (wg < L0_WGS + L1_WGS)  { role = 1; rwg = wg - L0_WGS; }
    else                            { role = 2; rwg = wg - L0_WGS - L1_WGS; }

    u32* flagL0 = flags;
    u32* flagL1 = flags + 64 * 16;
    u32* flagFC = flags + 128 * 16;
    u32* myflag = flags + wg * 16;

    {   // stage this WG's weight slice into LDS (once)
        const u16* src = (role == 0) ? (wl0g + rwg * 20480)
                       : (role == 1) ? (wl1g + rwg * 32768)
                                     : (wfcg + rwg * 16384);
        const int n4 = (role == 0) ? 2560 : (role == 1) ? 4096 : 2048;
        uint4* d4 = reinterpret_cast<uint4*>(wlds);
        const uint4* s4 = reinterpret_cast<const uint4*>(src);
        for (int i = tid; i < n4; i += 256) d4[i] = s4[i];
    }
    __syncthreads();

    const bf16x8* wp = reinterpret_cast<const bf16x8*>(wlds);
    const int wbase  = quad * 32 + nt * 16 + ci;     // + ks*128
    const int pcol   = rwg * 32 + nt * 16 + ci;      // permuted gate col (roles 0/1) or out col (fc)
    const int gateid = pcol & 3;                     // 0=i 1=f 2=g 3=o
    const float bias = (role == 0) ? bias0[pcol] : (role == 1) ? bias1[pcol] : fcb[pcol];
    const int brow0  = mt * 16 + quad * 4;           // C/D: batch of acc reg r is brow0+r
    const int arow   = mt * 16 + ci;                 // A-frag batch row
    const int jidx   = pcol >> 2;                    // h index owned (roles 0/1)

    float cst[4] = {0.f, 0.f, 0.f, 0.f};             // c-state, f32, replicated x4 lanes

    auto spin = [&](u32* f, int target) {
        if (target > 0)
            while ((int)__hip_atomic_load(f, __ATOMIC_RELAXED, __HIP_MEMORY_SCOPE_AGENT) < target)
                __builtin_amdgcn_s_sleep(1);
    };

    // epilogue: gates -> c,h; shfl-transpose so lanes ci<4 store one row's
    // 4 contiguous cols as a single aligned 8B atomic (16 stores per WG).
    auto epi = [&](const f32x4& acc, u16* slotb) {
        float ga[4], hv[4];
        #pragma unroll
        for (int r = 0; r < 4; ++r) {
            float g  = acc[r] + bias;
            float sv = 1.0f / (1.0f + __expf(-g));
            float tv = 1.0f - 2.0f / (__expf(2.0f * g) + 1.0f);
            ga[r] = (gateid == 2) ? tv : sv;
        }
        const int bl = lane & ~3;
        #pragma unroll
        for (int r = 0; r < 4; ++r) {
            float iv = __shfl(ga[r], bl + 0);
            float fv = __shfl(ga[r], bl + 1);
            float gv = __shfl(ga[r], bl + 2);
            float ov = __shfl(ga[r], bl + 3);
            float cn = fv * cst[r] + iv * gv;
            cst[r] = cn;
            hv[r] = ov * (1.0f - 2.0f / (__expf(2.0f * cn) + 1.0f));
        }
        u32 lo = 0, hi = 0;
        #pragma unroll
        for (int r = 0; r < 4; ++r) {                // gather row brow0+r into lane ci==r
            float c0 = __shfl(hv[r], (quad << 4) + 0);   // jidx = rwg*8+nt*4+0
            float c1 = __shfl(hv[r], (quad << 4) + 4);   // +1
            float c2 = __shfl(hv[r], (quad << 4) + 8);   // +2
            float c3 = __shfl(hv[r], (quad << 4) + 12);  // +3
            if (ci == r) {
                lo = (u32)f2bf(c0) | ((u32)f2bf(c1) << 16);
                hi = (u32)f2bf(c2) | ((u32)f2bf(c3) << 16);
            }
        }
        if (ci < 4) {
            u64* dst = reinterpret_cast<u64*>(slotb) + (brow0 + ci) * 128 + rwg * 2 + nt;
            u64 val = (u64)lo | ((u64)hi << 32);
            __hip_atomic_store(dst, val, __ATOMIC_RELAXED, __HIP_MEMORY_SCOPE_AGENT);
        }
    };

    auto fcTile = [&](const u16* aRow) -> f32x4 {
        u32x4 av[16];
        #pragma unroll
        for (int ks = 0; ks < 16; ++ks) av[ks] = load_llc(aRow + ks * 32);
        f32x4 accA = {0.f, 0.f, 0.f, 0.f}, accB = {0.f, 0.f, 0.f, 0.f};
        #pragma unroll
        for (int ks = 0; ks < 16; ++ks) {
            u32x4 v = av[ks];
            v[0] = relu2(v[0]); v[1] = relu2(v[1]); v[2] = relu2(v[2]); v[3] = relu2(v[3]);
            bf16x8 bv = wp[wbase + ks * 128];
            if (ks & 1) accB = __builtin_amdgcn_mfma_f32_16x16x32_bf16(as_bf(v), bv, accB, 0, 0, 0);
            else        accA = __builtin_amdgcn_mfma_f32_16x16x32_bf16(as_bf(v), bv, accA, 0, 0, 0);
        }
        return accA + accB;
    };

    if (role == 0) {
        u32* pf = (tid < 64) ? (flagL0 + tid * 16) : (tid < 128) ? (flagL1 + (tid - 64) * 16) : nullptr;
        const int po = (tid < 64) ? 0 : -3;
        for (int t = 0; t < T_STEPS; ++t) {
            // x-part MFMAs don't depend on h: do them before the wait (normal cached loads)
            const u16* xA = xbf + (arow * T_STEPS + t) * INDIM + quad * 8;
            f32x4 accA = {0.f, 0.f, 0.f, 0.f}, accB = {0.f, 0.f, 0.f, 0.f};
            u32x4 xv[4];
            #pragma unroll
            for (int k4 = 0; k4 < 4; ++k4) xv[k4] = *reinterpret_cast<const u32x4*>(xA + k4 * 32);
            #pragma unroll
            for (int k4 = 0; k4 < 4; ++k4) {
                bf16x8 bv = wp[wbase + (16 + k4) * 128];
                if (k4 & 1) accB = __builtin_amdgcn_mfma_f32_16x16x32_bf16(as_bf(xv[k4]), bv, accB, 0, 0, 0);
                else        accA = __builtin_amdgcn_mfma_f32_16x16x32_bf16(as_bf(xv[k4]), bv, accA, 0, 0, 0);
            }
            if (pf) spin(pf, t + po);
            __syncthreads();
            const u16* hA = h0ring + ((t + 3) & 3) * BH + arow * HID + quad * 8;
            u32x4 hvv[16];
            #pragma unroll
            for (int ks = 0; ks < 16; ++ks) hvv[ks] = load_llc(hA + ks * 32);
            HMFMA16(hvv, 0);
            epi(accA + accB, h0ring + (t & 3) * BH);
            vm0();                                    // h stores complete at LLC
            __syncthreads();
            if (tid == 0)
                __hip_atomic_store(myflag, (u32)(t + 1), __ATOMIC_RELAXED, __HIP_MEMORY_SCOPE_AGENT);
        }
    } else if (role == 1) {
        u32* pf = (tid < 64)  ? (flagL0 + tid * 16)
                : (tid < 128) ? (flagL1 + (tid - 64) * 16)
                : (tid < 132) ? (flagFC + (tid - 128) * 16) : nullptr;
        const int po = (tid < 64) ? 1 : (tid < 128) ? 0 : -3;
        for (int t = 0; t < T_STEPS; ++t) {
            if (pf) spin(pf, t + po);
            __syncthreads();
            const u16* h0A = h0ring + (t & 3) * BH + arow * HID + quad * 8;
            const u16* h1A = h1ring + ((t + 3) & 3) * BH + arow * HID + quad * 8;
            u32x4 h0v[16], h1v[16];
            #pragma unroll
            for (int ks = 0; ks < 16; ++ks) h0v[ks] = load_llc(h0A + ks * 32);
            #pragma unroll
            for (int ks = 0; ks < 16; ++ks) h1v[ks] = load_llc(h1A + ks * 32);
            f32x4 accA = {0.f, 0.f, 0.f, 0.f}, accB = {0.f, 0.f, 0.f, 0.f};
            HMFMA16(h0v, 0);                          // K 0..511: h0[t] (W_ih1)
            HMFMA16(h1v, 16);                         // K 512..1023: h1[t-1] (W_hh1)
            epi(accA + accB, h1ring + (t & 3) * BH);
            vm0();                                    // h stores complete at LLC
            __syncthreads();
            if (tid == 0)
                __hip_atomic_store(myflag, (u32)(t + 1), __ATOMIC_RELAXED, __HIP_MEMORY_SCOPE_AGENT);
        }
    } else {
        u32* pf = (tid < 64) ? (flagL1 + tid * 16) : nullptr;
        for (int t = 0; t < T_STEPS; ++t) {
            if (pf) spin(pf, t + 1);
            __syncthreads();
            const u16* h1A = h1ring + (t & 3) * BH + arow * HID + quad * 8;
            f32x4 acc = fcTile(h1A);
            #pragma unroll
            for (int r = 0; r < 4; ++r)
                dout[((brow0 + r) * T_STEPS + t) * OUTD + pcol] = acc[r] + bias;
            __syncthreads();                          // all reads of slot done before flag
            if (tid == 0)                             // reads complete before their MFMA uses
                __hip_atomic_store(myflag, (u32)(t + 1), __ATOMIC_RELAXED, __HIP_MEMORY_SCOPE_AGENT);
        }
        // hidden = fc(relu(h_n)); h[T-1] lives in slot 3 of each ring (2047 & 3 == 3)
        for (int l = 0; l < 2; ++l) {
            const u16* aR = (l == 0 ? h0ring : h1ring) + 3 * BH + arow * HID + quad * 8;
            f32x4 hh = fcTile(aR);
            #pragma unroll
            for (int r = 0; r < 4; ++r)
                dout[HID_OFF + (l * BATCH + brow0 + r) * OUTD + pcol] = hh[r] + bias;
        }
    }

    // c_n output [2, 32, 512]
    if (role <= 1 && (ci & 3) == 0) {
        #pragma unroll
        for (int r = 0; r < 4; ++r)
            dout[CN_OFF + (role * BATCH + brow0 + r) * HID + jidx] = cst[r];
    }
}

// ---------------- launch ----------------

extern "C" void kernel_launch(void* const* d_in, const int* in_sizes, int n_in,
                              void* d_out, int out_size, void* d_ws, size_t ws_size,
                              hipStream_t stream) {
    const float* x    = (const float*)d_in[0];
    const float* wih0 = (const float*)d_in[1];
    const float* whh0 = (const float*)d_in[2];
    const float* bih0 = (const float*)d_in[3];
    const float* bhh0 = (const float*)d_in[4];
    const float* wih1 = (const float*)d_in[5];
    const float* whh1 = (const float*)d_in[6];
    const float* bih1 = (const float*)d_in[7];
    const float* bhh1 = (const float*)d_in[8];
    const float* fcw  = (const float*)d_in[9];
    const float* fcb  = (const float*)d_in[10];

    char* ws = (char*)d_ws;
    u32*  flags = (u32*)(ws + WS_FLAGS);
    u16*  h0r   = (u16*)(ws + WS_H0RING);
    u16*  h1r   = (u16*)(ws + WS_H1RING);
    float* b0   = (float*)(ws + WS_BIAS0);
    float* b1   = (float*)(ws + WS_BIAS1);
    u16*  wfc   = (u16*)(ws + WS_WFC);
    u16*  wl0   = (u16*)(ws + WS_WL0);
    u16*  wl1   = (u16*)(ws + WS_WL1);
    u16*  xbf   = (u16*)(ws + WS_XBF);
    float* dout = (float*)d_out;

    // zero flags + h rings (ws is re-poisoned before every timed call)
    k_zero<<<272, 256, 0, stream>>>((u32*)ws, 69632);
    k_bias<<<8, 256, 0, stream>>>(bih0, bhh0, bih1, bhh1, b0, b1);
    k_xconv<<<8192, 256, 0, stream>>>(x, xbf);
    k_wconv<<<13568, 256, 0, stream>>>(wih0, whh0, wih1, whh1, fcw, wl0, wl1, wfc);
    k_lstm<<<GRID, 256, 0, stream>>>(xbf, wl0, wl1, wfc, b0, b1, fcb,
                                     h0r, h1r, flags, dout);
}

// Round 5
// 8891.824 us; speedup vs baseline: 3.6927x; 2.0861x over previous
//
#include <hip/hip_runtime.h>

typedef unsigned int u32;
typedef unsigned short u16;
typedef unsigned long long u64;

#define T_STEPS 2048
#define BATCH   32
#define HID     512
#define INDIM   128
#define OUTD    128
#define NG      2048
#define L0_WGS  64
#define L1_WGS  64
#define FC_WGS  4
#define NWG     (L0_WGS + L1_WGS + FC_WGS)
#define BH      (BATCH * HID)

#define HID_OFF 8388608           // 32*2048*128
#define CN_OFF  8396800           // + 2*32*128

// ws layout (bytes) — identical to v0
#define WS_FLAGS   0                         // 132 flags, 64B stride (16 KB reserved)
#define WS_H0RING  16384
#define WS_H1RING  (WS_H0RING + 131072)      // 4*32*512*2
#define WS_BIAS0   (WS_H1RING + 131072)
#define WS_BIAS1   (WS_BIAS0 + 8192)
#define WS_WFC     (WS_BIAS1 + 8192)         // 4 * 16384 u16
#define WS_WL0     (WS_WFC + 131072)         // 64 * 20480 u16
#define WS_WL1     (WS_WL0 + 2621440)        // 64 * 32768 u16
#define WS_XBF     (WS_WL1 + 4194304)        // 32*2048*128 u16

typedef __bf16 bf16x8 __attribute__((ext_vector_type(8)));
typedef float  f32x4  __attribute__((ext_vector_type(4)));
typedef unsigned int u32x4 __attribute__((ext_vector_type(4)));

__device__ __forceinline__ u16 f2bf(float f) {
    u32 u = __float_as_uint(f);
    u32 r = u + 0x7FFFu + ((u >> 16) & 1u);
    return (u16)(r >> 16);
}

union UB2 { u32x4 u; bf16x8 b; };
__device__ __forceinline__ bf16x8 as_bf(u32x4 u) { UB2 x; x.u = u; return x.b; }

__device__ __forceinline__ u32 relu2(u32 u) {
    u32 lo = (u & 0x8000u)     ? 0u : (u & 0xFFFFu);
    u32 hi = (u & 0x80000000u) ? 0u : (u & 0xFFFF0000u);
    return lo | hi;
}

// 16B LLC-bypass load (sc0 sc1: past L1 and L2, served at the coherence
// point). NON-atomic encoding, half the request count of 2x8B atomics.
// NOTE: no implicit waitcnt — caller must wait_vm0() before use.
__device__ __forceinline__ u32x4 ld16_llc(const void* p) {
    u32x4 r;
    asm volatile("global_load_dwordx4 %0, %1, off sc0 sc1"
                 : "=v"(r) : "v"(p) : "memory");
    return r;
}
__device__ __forceinline__ void wait_vm0() {
    asm volatile("s_waitcnt vmcnt(0)" ::: "memory");
    __builtin_amdgcn_sched_barrier(0);
}
__device__ __forceinline__ void vm0() {          // drain own stores to coherence point
    asm volatile("s_waitcnt vmcnt(0)" ::: "memory");
}

// ---------------- prep kernels (unchanged from v0) ----------------

__global__ void k_zero(u32* dst, int n) {
    int i = blockIdx.x * blockDim.x + threadIdx.x;
    if (i < n) dst[i] = 0u;
}

__global__ void k_bias(const float* __restrict__ bih0, const float* __restrict__ bhh0,
                       const float* __restrict__ bih1, const float* __restrict__ bhh1,
                       float* __restrict__ bias0, float* __restrict__ bias1) {
    int i = blockIdx.x * blockDim.x + threadIdx.x;
    if (i < NG) {
        int orig = (i & 3) * HID + (i >> 2);
        bias0[i] = bih0[orig] + bhh0[orig];
        bias1[i] = bih1[orig] + bhh1[orig];
    }
}

__global__ void k_xconv(const float* __restrict__ x, u16* __restrict__ xbf) {
    int i = blockIdx.x * blockDim.x + threadIdx.x;   // exactly 2097152 threads
    float4 v = reinterpret_cast<const float4*>(x)[i];
    u32 lo = (u32)f2bf(v.x) | ((u32)f2bf(v.y) << 16);
    u32 hi = (u32)f2bf(v.z) | ((u32)f2bf(v.w) << 16);
    reinterpret_cast<uint2*>(xbf)[i] = make_uint2(lo, hi);
}

// LDS-ready layout per WG: [ks][kb(4)][n(32)][8], value = W[p = wg*32+n][k = 32ks+8kb+j]
__global__ void k_wconv(const float* __restrict__ wih0, const float* __restrict__ whh0,
                        const float* __restrict__ wih1, const float* __restrict__ whh1,
                        const float* __restrict__ fcw,
                        u16* __restrict__ wl0, u16* __restrict__ wl1, u16* __restrict__ wfc) {
    int i = blockIdx.x * blockDim.x + threadIdx.x;   // exactly 3473408 threads
    if (i < 64 * 20480) {                            // layer0: K=640 (512 hh + 128 ih)
        int wg = i / 20480, r = i % 20480;
        int ks = r / 1024, kb = (r % 1024) / 256, n = (r % 256) / 8, j = r % 8;
        int k = ks * 32 + kb * 8 + j;
        int p = wg * 32 + n;
        int orig = (p & 3) * HID + (p >> 2);
        float v = (k < HID) ? whh0[orig * HID + k] : wih0[orig * INDIM + (k - HID)];
        wl0[i] = f2bf(v);
        return;
    }
    int i1 = i - 64 * 20480;
    if (i1 < 64 * 32768) {                           // layer1: K=1024 (512 ih(h0) + 512 hh(h1))
        int wg = i1 / 32768, r = i1 % 32768;
        int ks = r / 1024, kb = (r % 1024) / 256, n = (r % 256) / 8, j = r % 8;
        int k = ks * 32 + kb * 8 + j;
        int p = wg * 32 + n;
        int orig = (p & 3) * HID + (p >> 2);
        float v = (k < HID) ? wih1[orig * HID + k] : whh1[orig * HID + (k - HID)];
        wl1[i1] = f2bf(v);
        return;
    }
    int i2 = i1 - 64 * 32768;
    if (i2 < 4 * 16384) {                            // fc: K=512, no row permutation
        int wg = i2 / 16384, r = i2 % 16384;
        int ks = r / 1024, kb = (r % 1024) / 256, n = (r % 256) / 8, j = r % 8;
        int k = ks * 32 + kb * 8 + j;
        int o = wg * 32 + n;
        wfc[i2] = f2bf(fcw[o * HID + k]);
    }
}

// ---------------- persistent fused LSTM ----------------
//
// v0 flag protocol EXACTLY (known-good).  Data-path change only:
//  * h-matrix reads: each WG stages the needed ring slot(s) into LDS with a
//    cooperative 16B sc0sc1 bypass load — every 16B chunk read from the LLC
//    exactly ONCE per WG (v0 read it twice, as 2x8B atomics => 4x requests).
//  * MFMA A-fragments then come from LDS (XOR-swizzled rows).
//  * 128 KB static LDS (64 KB weights + 2x32 KB h stage) => 1 WG/CU (as v0).

__global__ __launch_bounds__(256, 1)
void k_lstm(const u16* __restrict__ xbf,
            const u16* __restrict__ wl0g, const u16* __restrict__ wl1g, const u16* __restrict__ wfcg,
            const float* __restrict__ bias0, const float* __restrict__ bias1, const float* __restrict__ fcb,
            u16* __restrict__ h0ring, u16* __restrict__ h1ring,
            u32* __restrict__ flags, float* __restrict__ dout)
{
    __shared__ u16   wlds[32768];                    // 64 KB weights
    __shared__ u32x4 hstage[2][2048];                // 2 x 32 KB h staging
    const int tid  = threadIdx.x;
    const int lane = tid & 63;
    const int wv   = tid >> 6;
    const int mt   = wv >> 1;                        // batch-half tile
    const int nt   = wv & 1;                         // col tile
    const int ci   = lane & 15;
    const int quad = lane >> 4;
    const int wg   = blockIdx.x;

    int role, rwg;
    if      (wg < L0_WGS)           { role = 0; rwg = wg; }
    else if (wg < L0_WGS + L1_WGS)  { role = 1; rwg = wg - L0_WGS; }
    else                            { role = 2; rwg = wg - L0_WGS - L1_WGS; }

    u32* flagL0 = flags;
    u32* flagL1 = flags + 64 * 16;
    u32* flagFC = flags + 128 * 16;
    u32* myflag = flags + wg * 16;

    {   // stage this WG's weight slice into LDS (once)
        const u16* src = (role == 0) ? (wl0g + rwg * 20480)
                       : (role == 1) ? (wl1g + rwg * 32768)
                                     : (wfcg + rwg * 16384);
        const int n4 = (role == 0) ? 2560 : (role == 1) ? 4096 : 2048;
        uint4* d4 = reinterpret_cast<uint4*>(wlds);
        const uint4* s4 = reinterpret_cast<const uint4*>(src);
        for (int i = tid; i < n4; i += 256) d4[i] = s4[i];
    }
    __syncthreads();

    const bf16x8* wp = reinterpret_cast<const bf16x8*>(wlds);
    const int wbase  = quad * 32 + nt * 16 + ci;     // + ks*128
    const int pcol   = rwg * 32 + nt * 16 + ci;      // permuted gate col (roles 0/1) or out col (fc)
    const int gateid = pcol & 3;                     // 0=i 1=f 2=g 3=o
    const float bias = (role == 0) ? bias0[pcol] : (role == 1) ? bias1[pcol] : fcb[pcol];
    const int brow0  = mt * 16 + quad * 4;           // C/D: batch of acc reg r is brow0+r
    const int arow   = mt * 16 + ci;                 // A-frag batch row
    const int jidx   = pcol >> 2;                    // h index owned (roles 0/1)
    const int hfrag  = arow * 64 + quad;             // LDS chunk base for fragments
    const int hswz   = arow & 7;                     // row XOR swizzle

    float cst[4] = {0.f, 0.f, 0.f, 0.f};             // c-state, f32, replicated x4 lanes

    auto spin = [&](u32* f, int target) {
        if (target > 0)
            while ((int)__hip_atomic_load(f, __ATOMIC_RELAXED, __HIP_MEMORY_SCOPE_AGENT) < target)
                __builtin_amdgcn_s_sleep(1);
    };

    // cooperative LLC->LDS stage of one 32KB slot (2048 x 16B), 8 chunks/thread
    auto stage1 = [&](const u16* slot, int buf) {
        u32x4 b[8];
        #pragma unroll
        for (int r = 0; r < 8; ++r) b[r] = ld16_llc(slot + (tid + r * 256) * 8);
        wait_vm0();
        #pragma unroll
        for (int r = 0; r < 8; ++r) {
            int c = tid + r * 256;
            hstage[buf][c ^ ((c >> 6) & 7)] = b[r];
        }
    };
    auto stage2 = [&](const u16* s0, const u16* s1) {   // both slots, one drain
        u32x4 b0[8], b1[8];
        #pragma unroll
        for (int r = 0; r < 8; ++r) b0[r] = ld16_llc(s0 + (tid + r * 256) * 8);
        #pragma unroll
        for (int r = 0; r < 8; ++r) b1[r] = ld16_llc(s1 + (tid + r * 256) * 8);
        wait_vm0();
        #pragma unroll
        for (int r = 0; r < 8; ++r) {
            int c = tid + r * 256;
            int cs = c ^ ((c >> 6) & 7);
            hstage[0][cs] = b0[r];
            hstage[1][cs] = b1[r];
        }
    };

    // epilogue: gates -> c,h; shfl-transpose; one aligned 8B agent store per active lane
    auto epi = [&](const f32x4& acc, u16* slotb) {
        float ga[4], hv[4];
        #pragma unroll
        for (int r = 0; r < 4; ++r) {
            float g  = acc[r] + bias;
            float sv = 1.0f / (1.0f + __expf(-g));
            float tv = 1.0f - 2.0f / (__expf(2.0f * g) + 1.0f);
            ga[r] = (gateid == 2) ? tv : sv;
        }
        const int bl = lane & ~3;
        #pragma unroll
        for (int r = 0; r < 4; ++r) {
            float iv = __shfl(ga[r], bl + 0);
            float fv = __shfl(ga[r], bl + 1);
            float gv = __shfl(ga[r], bl + 2);
            float ov = __shfl(ga[r], bl + 3);
            float cn = fv * cst[r] + iv * gv;
            cst[r] = cn;
            hv[r] = ov * (1.0f - 2.0f / (__expf(2.0f * cn) + 1.0f));
        }
        u32 lo = 0, hi = 0;
        #pragma unroll
        for (int r = 0; r < 4; ++r) {                // gather row brow0+r into lane ci==r
            float c0 = __shfl(hv[r], (quad << 4) + 0);   // jidx = rwg*8+nt*4+0
            float c1 = __shfl(hv[r], (quad << 4) + 4);   // +1
            float c2 = __shfl(hv[r], (quad << 4) + 8);   // +2
            float c3 = __shfl(hv[r], (quad << 4) + 12);  // +3
            if (ci == r) {
                lo = (u32)f2bf(c0) | ((u32)f2bf(c1) << 16);
                hi = (u32)f2bf(c2) | ((u32)f2bf(c3) << 16);
            }
        }
        if (ci < 4) {
            u64* dst = reinterpret_cast<u64*>(slotb) + (brow0 + ci) * 128 + rwg * 2 + nt;
            u64 val = (u64)lo | ((u64)hi << 32);
            __hip_atomic_store(dst, val, __ATOMIC_RELAXED, __HIP_MEMORY_SCOPE_AGENT);
        }
    };

    // 16 MFMAs with A-fragments from LDS stage buffer
    #define HMFMA16S(BUF, KSOFF)                                                 \
        _Pragma("unroll")                                                        \
        for (int _k = 0; _k < 16; ++_k) {                                        \
          u32x4 _hv = hstage[BUF][(hfrag + _k * 4) ^ hswz];                      \
          bf16x8 _bv = wp[wbase + (_k + (KSOFF)) * 128];                         \
          if (_k & 1) accB = __builtin_amdgcn_mfma_f32_16x16x32_bf16(as_bf(_hv), _bv, accB, 0, 0, 0); \
          else        accA = __builtin_amdgcn_mfma_f32_16x16x32_bf16(as_bf(_hv), _bv, accA, 0, 0, 0); \
        }

    auto fcTileS = [&](int buf) -> f32x4 {           // fc tile from staged h (with relu)
        f32x4 accA = {0.f,0.f,0.f,0.f}, accB = {0.f,0.f,0.f,0.f};
        #pragma unroll
        for (int ks = 0; ks < 16; ++ks) {
            u32x4 v = hstage[buf][(hfrag + ks * 4) ^ hswz];
            v[0] = relu2(v[0]); v[1] = relu2(v[1]); v[2] = relu2(v[2]); v[3] = relu2(v[3]);
            bf16x8 bv = wp[wbase + ks * 128];
            if (ks & 1) accB = __builtin_amdgcn_mfma_f32_16x16x32_bf16(as_bf(v), bv, accB, 0, 0, 0);
            else        accA = __builtin_amdgcn_mfma_f32_16x16x32_bf16(as_bf(v), bv, accA, 0, 0, 0);
        }
        return accA + accB;
    };

    if (role == 0) {
        u32* pf = (tid < 64) ? (flagL0 + tid * 16) : (tid < 128) ? (flagL1 + (tid - 64) * 16) : nullptr;
        const int po = (tid < 64) ? 0 : -3;
        for (int t = 0; t < T_STEPS; ++t) {
            // x-part MFMAs don't depend on h: do them before the wait (normal cached loads)
            const u16* xA = xbf + (arow * T_STEPS + t) * INDIM + quad * 8;
            f32x4 accA = {0.f, 0.f, 0.f, 0.f}, accB = {0.f, 0.f, 0.f, 0.f};
            u32x4 xv[4];
            #pragma unroll
            for (int k4 = 0; k4 < 4; ++k4) xv[k4] = *reinterpret_cast<const u32x4*>(xA + k4 * 32);
            #pragma unroll
            for (int k4 = 0; k4 < 4; ++k4) {
                bf16x8 bv = wp[wbase + (16 + k4) * 128];
                if (k4 & 1) accB = __builtin_amdgcn_mfma_f32_16x16x32_bf16(as_bf(xv[k4]), bv, accB, 0, 0, 0);
                else        accA = __builtin_amdgcn_mfma_f32_16x16x32_bf16(as_bf(xv[k4]), bv, accA, 0, 0, 0);
            }
            if (pf) spin(pf, t + po);
            __syncthreads();
            stage1(h0ring + ((t + 3) & 3) * BH, 0);   // h0[t-1], once per WG
            __syncthreads();
            HMFMA16S(0, 0);
            epi(accA + accB, h0ring + (t & 3) * BH);
            vm0();                                    // h stores complete at LLC
            __syncthreads();
            if (tid == 0)
                __hip_atomic_store(myflag, (u32)(t + 1), __ATOMIC_RELAXED, __HIP_MEMORY_SCOPE_AGENT);
        }
    } else if (role == 1) {
        u32* pf = (tid < 64)  ? (flagL0 + tid * 16)
                : (tid < 128) ? (flagL1 + (tid - 64) * 16)
                : (tid < 132) ? (flagFC + (tid - 128) * 16) : nullptr;
        const int po = (tid < 64) ? 1 : (tid < 128) ? 0 : -3;
        for (int t = 0; t < T_STEPS; ++t) {
            if (pf) spin(pf, t + po);
            __syncthreads();
            stage2(h0ring + (t & 3) * BH,             // h0[t]   -> buf 0
                   h1ring + ((t + 3) & 3) * BH);      // h1[t-1] -> buf 1
            __syncthreads();
            f32x4 accA = {0.f, 0.f, 0.f, 0.f}, accB = {0.f, 0.f, 0.f, 0.f};
            HMFMA16S(0, 0);                           // K 0..511: h0[t] (W_ih1)
            HMFMA16S(1, 16);                          // K 512..1023: h1[t-1] (W_hh1)
            epi(accA + accB, h1ring + (t & 3) * BH);
            vm0();                                    // h stores complete at LLC
            __syncthreads();
            if (tid == 0)
                __hip_atomic_store(myflag, (u32)(t + 1), __ATOMIC_RELAXED, __HIP_MEMORY_SCOPE_AGENT);
        }
    } else {
        u32* pf = (tid < 64) ? (flagL1 + tid * 16) : nullptr;
        for (int t = 0; t < T_STEPS; ++t) {
            if (pf) spin(pf, t + 1);
            __syncthreads();
            stage1(h1ring + (t & 3) * BH, 0);
            __syncthreads();
            f32x4 acc = fcTileS(0);
            #pragma unroll
            for (int r = 0; r < 4; ++r)
                dout[((brow0 + r) * T_STEPS + t) * OUTD + pcol] = acc[r] + bias;
            __syncthreads();                          // all reads of slot done before flag
            if (tid == 0)
                __hip_atomic_store(myflag, (u32)(t + 1), __ATOMIC_RELAXED, __HIP_MEMORY_SCOPE_AGENT);
        }
        // hidden = fc(relu(h_n)); h[T-1] lives in slot 3 of each ring (2047 & 3 == 3).
        // hstage[0] still holds h1[2047] from the last loop iteration.
        stage1(h0ring + 3 * BH, 1);
        __syncthreads();
        f32x4 hh1 = fcTileS(0);
        f32x4 hh0 = fcTileS(1);
        #pragma unroll
        for (int r = 0; r < 4; ++r)
            dout[HID_OFF + (brow0 + r) * OUTD + pcol] = hh0[r] + bias;
        #pragma unroll
        for (int r = 0; r < 4; ++r)
            dout[HID_OFF + (BATCH + brow0 + r) * OUTD + pcol] = hh1[r] + bias;
    }

    // c_n output [2, 32, 512]
    if (role <= 1 && (ci & 3) == 0) {
        #pragma unroll
        for (int r = 0; r < 4; ++r)
            dout[CN_OFF + (role * BATCH + brow0 + r) * HID + jidx] = cst[r];
    }
}

// ---------------- launch ----------------

extern "C" void kernel_launch(void* const* d_in, const int* in_sizes, int n_in,
                              void* d_out, int out_size, void* d_ws, size_t ws_size,
                              hipStream_t stream) {
    const float* x    = (const float*)d_in[0];
    const float* wih0 = (const float*)d_in[1];
    const float* whh0 = (const float*)d_in[2];
    const float* bih0 = (const float*)d_in[3];
    const float* bhh0 = (const float*)d_in[4];
    const float* wih1 = (const float*)d_in[5];
    const float* whh1 = (const float*)d_in[6];
    const float* bih1 = (const float*)d_in[7];
    const float* bhh1 = (const float*)d_in[8];
    const float* fcw  = (const float*)d_in[9];
    const float* fcb  = (const float*)d_in[10];

    char* ws = (char*)d_ws;
    u32*  flags = (u32*)(ws + WS_FLAGS);
    u16*  h0r   = (u16*)(ws + WS_H0RING);
    u16*  h1r   = (u16*)(ws + WS_H1RING);
    float* b0   = (float*)(ws + WS_BIAS0);
    float* b1   = (float*)(ws + WS_BIAS1);
    u16*  wfc   = (u16*)(ws + WS_WFC);
    u16*  wl0   = (u16*)(ws + WS_WL0);
    u16*  wl1   = (u16*)(ws + WS_WL1);
    u16*  xbf   = (u16*)(ws + WS_XBF);
    float* dout = (float*)d_out;

    // zero flags + h rings (ws is re-poisoned before every timed call)
    k_zero<<<272, 256, 0, stream>>>((u32*)ws, 69632);
    k_bias<<<8, 256, 0, stream>>>(bih0, bhh0, bih1, bhh1, b0, b1);
    k_xconv<<<8192, 256, 0, stream>>>(x, xbf);
    k_wconv<<<13568, 256, 0, stream>>>(wih0, whh0, wih1, whh1, fcw, wl0, wl1, wfc);
    k_lstm<<<NWG, 256, 0, stream>>>(xbf, wl0, wl1, wfc, b0, b1, fcb,
                                    h0r, h1r, flags, dout);
}